// Round 9
// baseline (286.163 us; speedup 1.0000x reference)
//
#include <hip/hip_runtime.h>
#include <hip/hip_cooperative_groups.h>
#include <math.h>

#define NN 2048
#define INDIM 256
#define ODIM 64
#define NH 8
#define DHD 8
#define LOG2E 1.44269504088896340736f

typedef __attribute__((ext_vector_type(4))) float f32x4;
typedef __attribute__((ext_vector_type(8))) short s16x8;

namespace cg = cooperative_groups;

// Single cooperative kernel, 256 blocks x 1024 threads (1 block/CU).
// Phase1: wh=h@W^T+b (bf16, transposed [o][n]), ei/ej (x log2e) for 8 nodes.
// Phase2: block=(i-tile 16)x(j-half 1024); wave=(head, j-subhalf 512);
//         per 32-j step build P A-frag from ei+ej+mask, V B-frag from whT
//         (col 8 = ones -> denominator), one mfma_f32_16x16x32_bf16.
// Phase3: combine 4 partials per (h,i), divide, ELU, write out.
__global__ __launch_bounds__(1024) void gat_fused(
    const float* __restrict__ h, const int* __restrict__ adj,
    const float* __restrict__ Ww, const float* __restrict__ Wb,
    const float* __restrict__ aw, const float* __restrict__ ab,
    unsigned short* __restrict__ whT, float* __restrict__ eiT,
    float* __restrict__ ejT, float* __restrict__ pacc,
    float* __restrict__ out)
{
    __shared__ float s_ej[NH][1024];          // 32 KB (phase1 reuses as sH[8][256])
    __shared__ unsigned int s_mask[16][33];   // 2.1 KB, pad 33 vs bank conflicts
    const int t = threadIdx.x;
    const int b = blockIdx.x;
    cg::grid_group grid = cg::this_grid();

    // ---------------- phase 1: pre (8 nodes per block) ----------------
    {
        float (*sH)[INDIM] = (float(*)[INDIM])&s_ej[0][0];
        if (t < 512)
            ((float4*)&sH[0][0])[t] =
                ((const float4*)(h + (size_t)b * 8 * INDIM))[t];
        __syncthreads();
        if (t < 512) {
            const int o  = t & 63;
            const int nd = t >> 6;               // wave = node
            const int n  = b * 8 + nd;
            const float4* w4 = (const float4*)(Ww + (size_t)o * INDIM);
            float acc = 0.f;
#pragma unroll 8
            for (int k = 0; k < INDIM / 4; ++k) {
                const float4 wk = w4[k];
                const float4 hv = *(const float4*)&sH[nd][k * 4];
                acc = fmaf(wk.x, hv.x, acc); acc = fmaf(wk.y, hv.y, acc);
                acc = fmaf(wk.z, hv.z, acc); acc = fmaf(wk.w, hv.w, acc);
            }
            acc += Wb[o];
            {   // bf16 RNE pack, transposed store
                unsigned int u = __float_as_uint(acc);
                unsigned int r = (u + 0x7FFF + ((u >> 16) & 1)) >> 16;
                whT[(size_t)o * NN + n] = (unsigned short)r;
            }
            const int d = o & 7;
            float pi = acc * aw[d];
            float pj = acc * aw[NH + d];
            pi += __shfl_xor(pi, 1, 64); pj += __shfl_xor(pj, 1, 64);
            pi += __shfl_xor(pi, 2, 64); pj += __shfl_xor(pj, 2, 64);
            pi += __shfl_xor(pi, 4, 64); pj += __shfl_xor(pj, 4, 64);
            if (d == 0) {
                const int hd = o >> 3;
                eiT[(size_t)hd * NN + n] = (pi + ab[0]) * LOG2E;
                ejT[(size_t)hd * NN + n] = pj * LOG2E;
            }
        }
    }
    __threadfence();
    grid.sync();

    // ---------------- phase 2: MFMA edge work ----------------
    const int it2 = b >> 1, jq = b & 1;
    const int i0 = it2 * 16, j0 = jq * 1024;
    {
        if (t < 512) {   // stage adj bitmasks: 16 rows x 32 words
            const int row = t >> 5, w = t & 31;
            const int* ap = adj + (size_t)(i0 + row) * NN + j0 + w * 32;
            unsigned int m = 0;
#pragma unroll
            for (int q = 0; q < 8; ++q) {
                const int4 v = ((const int4*)ap)[q];
                m |= (unsigned)(v.x != 0) << (q * 4 + 0);
                m |= (unsigned)(v.y != 0) << (q * 4 + 1);
                m |= (unsigned)(v.z != 0) << (q * 4 + 2);
                m |= (unsigned)(v.w != 0) << (q * 4 + 3);
            }
            s_mask[row][w] = m;
        }
        // stage ej half: 8 heads x 1024 = 2048 float4, 2 per thread
#pragma unroll
        for (int k = 0; k < 2; ++k) {
            const int f  = t + k * 1024;         // float4 index
            const int hh = f >> 8;               // 256 float4 per head
            const int of = (f & 255) * 4;
            *(float4*)&s_ej[hh][of] =
                *(const float4*)(ejT + (size_t)hh * NN + j0 + of);
        }
    }
    __syncthreads();

    {
        const int wv   = t >> 6;                 // 0..15
        const int hh   = wv & 7;                 // head
        const int half = wv >> 3;                // j-subhalf (0/1)
        const int l    = t & 63;
        const int row  = l & 15;                 // A m-index AND B col
        const int g    = l >> 4;                 // k-group
        const float eirow = eiT[(size_t)hh * NN + i0 + row];

        const unsigned short* vbase =
            whT + (size_t)(hh * DHD + row) * NN + j0 + half * 512 + g * 8;
        union { unsigned int u[4]; s16x8 v; } bconst;
        {   // col 8 = ones (bf16 1.0), cols 9..15 = 0
            const unsigned int cv = (row == 8) ? 0x3F803F80u : 0u;
            bconst.u[0] = cv; bconst.u[1] = cv; bconst.u[2] = cv; bconst.u[3] = cv;
        }

        f32x4 acc = {0.f, 0.f, 0.f, 0.f};

        for (int step = 0; step < 16; ++step) {  // 512 j's per wave
            const unsigned int mbyte =
                (s_mask[row][half * 16 + step] >> (g * 8)) & 0xFFu;
            const int base = half * 512 + step * 32 + g * 8;
            const float4 ea = *(const float4*)&s_ej[hh][base];
            const float4 eb = *(const float4*)&s_ej[hh][base + 4];

            float p[8];
            p[0] = eirow + ea.x; p[1] = eirow + ea.y;
            p[2] = eirow + ea.z; p[3] = eirow + ea.w;
            p[4] = eirow + eb.x; p[5] = eirow + eb.y;
            p[6] = eirow + eb.z; p[7] = eirow + eb.w;
#pragma unroll
            for (int i = 0; i < 8; ++i) {
                float s = fmaxf(p[i], 0.2f * p[i]);      // LeakyReLU (scaled)
                s = (mbyte & (1u << i)) ? s : -192.0f;   // mask: exp2 -> 0
                p[i] = __builtin_amdgcn_exp2f(s);
            }
            union { unsigned int u[4]; s16x8 v; } af;
#pragma unroll
            for (int q = 0; q < 4; ++q)
                asm("v_cvt_pk_bf16_f32 %0, %1, %2"
                    : "=v"(af.u[q]) : "v"(p[2 * q]), "v"(p[2 * q + 1]));

            s16x8 bf;
            if (row < DHD) bf = *(const s16x8*)(vbase + step * 32);
            else           bf = bconst.v;

            acc = __builtin_amdgcn_mfma_f32_16x16x32_bf16(af.v, bf, acc, 0, 0, 0);
        }

        const int q2 = jq * 2 + half;            // partial slot 0..3
#pragma unroll
        for (int r = 0; r < 4; ++r) {
            const int orow = g * 4 + r;
            pacc[(((size_t)(q2 * NH + hh)) * NN + (i0 + orow)) * 16 + row] = acc[r];
        }
    }
    __threadfence();
    grid.sync();

    // ---------------- phase 3: combine + ELU + store ----------------
    if (t < 512) {
        const int gid = b * 512 + t;             // < 131072
        const int d  = gid & 7;
        const int i  = (gid >> 3) & (NN - 1);
        const int hh = gid >> 14;
        float v = 0.f, dn = 0.f;
#pragma unroll
        for (int q = 0; q < 4; ++q) {
            const float* p = pacc + (((size_t)(q * NH + hh)) * NN + i) * 16;
            v  += p[d];
            dn += p[8];
        }
        float r = v / dn;
        r = (r > 0.f) ? r : expm1f(r);           // ELU(alpha=1)
        out[gid] = r;                            // gid == hh*16384 + i*8 + d
    }
}

extern "C" void kernel_launch(void* const* d_in, const int* in_sizes, int n_in,
                              void* d_out, int out_size, void* d_ws, size_t ws_size,
                              hipStream_t stream) {
    const float* h   = (const float*)d_in[0];
    const int*   adj = (const int*)d_in[1];
    const float* Ww  = (const float*)d_in[2];
    const float* Wb  = (const float*)d_in[3];
    const float* aw  = (const float*)d_in[4];
    const float* ab  = (const float*)d_in[5];
    float* out = (float*)d_out;

    char* ws = (char*)d_ws;
    unsigned short* whT = (unsigned short*)ws;            // 256 KB  [o][n]
    float* eiT  = (float*)(ws + 262144);                  // 64 KB   [h][n]
    float* ejT  = (float*)(ws + 327680);                  // 64 KB   [h][n]
    float* pacc = (float*)(ws + 393216);                  // 4 MB [q][h][n][16]

    void* args[] = {(void*)&h, (void*)&adj, (void*)&Ww, (void*)&Wb,
                    (void*)&aw, (void*)&ab, (void*)&whT, (void*)&eiT,
                    (void*)&ejT, (void*)&pacc, (void*)&out};
    hipLaunchCooperativeKernel((const void*)gat_fused, dim3(256), dim3(1024),
                               args, 0, stream);
}

// Round 10
// 41.113 us; speedup vs baseline: 6.9604x; 6.9604x over previous
//
#include <hip/hip_runtime.h>
#include <math.h>

#define NN 2048
#define INDIM 256
#define ODIM 64
#define NH 8
#define DHD 8
#define LOG2E 1.44269504088896340736f
#define JQ 4
#define JQL (NN / JQ)     // 512
#define ITILE 16

typedef __attribute__((ext_vector_type(4))) float f32x4;
typedef __attribute__((ext_vector_type(8))) short s16x8;

// K1: wh = h@W^T + b, stored TRANSPOSED bf16 whT[o=h*8+d][n];
// eiT[h][n] = (ei+ab)*log2e ; ejT[h][n] = ej*log2e. (layouts match gat_mfma's
// coalesced B-fragment loads). 512 blocks x 256 thr, 4 nodes/block.
__global__ __launch_bounds__(256) void gat_pre(
    const float* __restrict__ h, const float* __restrict__ Ww,
    const float* __restrict__ Wb, const float* __restrict__ aw,
    const float* __restrict__ ab,
    unsigned short* __restrict__ whT, float* __restrict__ eiT,
    float* __restrict__ ejT)
{
    __shared__ float sH[4][INDIM];           // 4 KB
    const int t = threadIdx.x;
    const int n0 = blockIdx.x * 4;
    ((float4*)&sH[0][0])[t] = ((const float4*)(h + (size_t)n0 * INDIM))[t];
    __syncthreads();

    const int o  = t & 63;
    const int wv = t >> 6;                   // node within block
    const int n  = n0 + wv;
    const float4* w4 = (const float4*)(Ww + (size_t)o * INDIM);
    float acc = 0.f;
#pragma unroll 8
    for (int k = 0; k < INDIM / 4; ++k) {
        const float4 wk = w4[k];
        const float4 hv = *(const float4*)&sH[wv][k * 4];
        acc = fmaf(wk.x, hv.x, acc); acc = fmaf(wk.y, hv.y, acc);
        acc = fmaf(wk.z, hv.z, acc); acc = fmaf(wk.w, hv.w, acc);
    }
    acc += Wb[o];

    {   // bf16 RNE pack, transposed store
        unsigned int u = __float_as_uint(acc);
        unsigned int r = (u + 0x7FFF + ((u >> 16) & 1)) >> 16;
        whT[(size_t)o * NN + n] = (unsigned short)r;
    }

    const int d = o & 7;
    float pi = acc * aw[d];
    float pj = acc * aw[NH + d];
    pi += __shfl_xor(pi, 1, 64); pj += __shfl_xor(pj, 1, 64);
    pi += __shfl_xor(pi, 2, 64); pj += __shfl_xor(pj, 2, 64);
    pi += __shfl_xor(pi, 4, 64); pj += __shfl_xor(pj, 4, 64);
    if (d == 0) {
        const int hd = o >> 3;
        eiT[(size_t)hd * NN + n] = (pi + ab[0]) * LOG2E;
        ejT[(size_t)hd * NN + n] = pj * LOG2E;
    }
}

// K2: MFMA edge kernel. Block = (i-tile 16) x (j-quarter 512), 512 thr =
// 8 waves, wave hh handles head hh. Per j-step(32): lane builds P A-frag
// (row=l&15, k=(l>>4)*8+i) in bf16, loads V B-frag (col=l&15; col 8 = ones
// column -> denominator free from MFMA), one mfma_f32_16x16x32_bf16.
// Writes 16x16 D-tile (cols 0..8 meaningful) as f32 partials to pacc.
__global__ __launch_bounds__(512) void gat_mfma(
    const int* __restrict__ adj, const unsigned short* __restrict__ whT,
    const float* __restrict__ eiT, const float* __restrict__ ejT,
    float* __restrict__ pacc)
{
    __shared__ unsigned int s_mask[ITILE][17];   // pad 17: conflict-free rows
    __shared__ float s_ej[NH][JQL];              // 16 KB
    const int t  = threadIdx.x;
    const int it = blockIdx.x >> 2;
    const int jq = blockIdx.x & 3;
    const int i0 = it * ITILE;
    const int j0 = jq * JQL;

    if (t < ITILE * 16) {                    // pack adj bits: word w = 32 j's
        const int row = t >> 4, w = t & 15;
        const int* ap = adj + (size_t)(i0 + row) * NN + j0 + w * 32;
        unsigned int b = 0;
#pragma unroll
        for (int q = 0; q < 8; ++q) {
            const int4 v = ((const int4*)ap)[q];
            b |= (unsigned)(v.x != 0) << (q * 4 + 0);
            b |= (unsigned)(v.y != 0) << (q * 4 + 1);
            b |= (unsigned)(v.z != 0) << (q * 4 + 2);
            b |= (unsigned)(v.w != 0) << (q * 4 + 3);
        }
        s_mask[row][w] = b;
    }
    for (int idx = t; idx < NH * JQL; idx += 512) {   // stage ej quarter
        const int hh = idx >> 9, jl = idx & 511;
        s_ej[hh][jl] = ejT[(size_t)hh * NN + j0 + jl];
    }
    __syncthreads();

    const int l   = t & 63;
    const int hh  = t >> 6;                  // wave = head
    const int row = l & 15;                  // A m-index AND B n-index (col)
    const int g   = l >> 4;                  // k-group (k = g*8 + i)
    const float eirow = eiT[(size_t)hh * NN + i0 + row];

    const unsigned short* vbase = whT + ((size_t)(hh * DHD + row)) * NN + j0 + g * 8;
    union { unsigned int u[4]; s16x8 v; } bconst;
    {   // col 8 -> ones column (bf16 1.0 = 0x3F80); cols 9..15 -> 0
        const unsigned int cv = (row == 8) ? 0x3F803F80u : 0u;
        bconst.u[0] = cv; bconst.u[1] = cv; bconst.u[2] = cv; bconst.u[3] = cv;
    }

    f32x4 acc = {0.f, 0.f, 0.f, 0.f};

    for (int step = 0; step < JQL / 32; ++step) {    // 16 steps
        const unsigned int mbyte = (s_mask[row][step] >> (g * 8)) & 0xFFu;
        const float4 ea = *(const float4*)&s_ej[hh][step * 32 + g * 8];
        const float4 eb = *(const float4*)&s_ej[hh][step * 32 + g * 8 + 4];

        float p[8];
        p[0] = eirow + ea.x; p[1] = eirow + ea.y;
        p[2] = eirow + ea.z; p[3] = eirow + ea.w;
        p[4] = eirow + eb.x; p[5] = eirow + eb.y;
        p[6] = eirow + eb.z; p[7] = eirow + eb.w;
#pragma unroll
        for (int i = 0; i < 8; ++i) {
            float s = fmaxf(p[i], 0.2f * p[i]);          // LeakyReLU (scaled)
            s = (mbyte & (1u << i)) ? s : -192.0f;       // mask: exp2 -> 0
            p[i] = __builtin_amdgcn_exp2f(s);
        }
        union { unsigned int u[4]; s16x8 v; } af;
#pragma unroll
        for (int q = 0; q < 4; ++q)
            asm("v_cvt_pk_bf16_f32 %0, %1, %2"
                : "=v"(af.u[q]) : "v"(p[2 * q]), "v"(p[2 * q + 1]));

        s16x8 bf;
        if (row < DHD) bf = *(const s16x8*)(vbase + step * 32);
        else           bf = bconst.v;

        acc = __builtin_amdgcn_mfma_f32_16x16x32_bf16(af.v, bf, acc, 0, 0, 0);
    }

    // D: row=(l>>4)*4+r, col=l&15 (verified layout). Store f32 partial tile.
#pragma unroll
    for (int r = 0; r < 4; ++r) {
        const int orow = g * 4 + r;
        pacc[(((size_t)(jq * NH + hh)) * NN + (i0 + orow)) * 16 + row] = acc[r];
    }
}

// K3: combine j-quarter partials, divide by den (col 8), ELU, write out.
__global__ __launch_bounds__(256) void gat_fin(
    const float* __restrict__ pacc, float* __restrict__ out)
{
    const int gid = blockIdx.x * 256 + threadIdx.x;   // < 131072
    const int d  = gid & 7;
    const int i  = (gid >> 3) & (NN - 1);
    const int hh = gid >> 14;
    float v = 0.f, dn = 0.f;
#pragma unroll
    for (int jq = 0; jq < JQ; ++jq) {
        const float* p = pacc + (((size_t)(jq * NH + hh)) * NN + i) * 16;
        v  += p[d];
        dn += p[8];
    }
    float r = v / dn;
    r = (r > 0.f) ? r : expm1f(r);           // ELU(alpha=1)
    out[gid] = r;                            // gid == hh*16384 + i*8 + d
}

extern "C" void kernel_launch(void* const* d_in, const int* in_sizes, int n_in,
                              void* d_out, int out_size, void* d_ws, size_t ws_size,
                              hipStream_t stream) {
    const float* h   = (const float*)d_in[0];
    const int*   adj = (const int*)d_in[1];
    const float* Ww  = (const float*)d_in[2];
    const float* Wb  = (const float*)d_in[3];
    const float* aw  = (const float*)d_in[4];
    const float* ab  = (const float*)d_in[5];
    float* out = (float*)d_out;

    char* ws = (char*)d_ws;
    unsigned short* whT = (unsigned short*)ws;            // 256 KB  [o][n]
    float* eiT  = (float*)(ws + 262144);                  // 64 KB   [h][n]
    float* ejT  = (float*)(ws + 327680);                  // 64 KB   [h][n]
    float* pacc = (float*)(ws + 393216);                  // 4 MB [jq][h][n][16]

    gat_pre<<<NN / 4, 256, 0, stream>>>(h, Ww, Wb, aw, ab, whT, eiT, ejT);
    gat_mfma<<<(NN / ITILE) * JQ, 512, 0, stream>>>(adj, whT, eiT, ejT, pacc);
    gat_fin<<<NN * ODIM / 256, 256, 0, stream>>>(pacc, out);
}